// Round 9
// baseline (164.572 us; speedup 1.0000x reference)
//
#include <hip/hip_runtime.h>
#include <cmath>

#define E_ 4
#define L_ 10
#define M_ 512
#define F_ 128
#define S_ 1000

typedef unsigned int u32;
typedef _Float16 f16;
typedef __attribute__((ext_vector_type(8))) _Float16 v8h;
typedef __attribute__((ext_vector_type(4))) float v4f;

__device__ __forceinline__ float fexp2(float a){
#if __has_builtin(__builtin_amdgcn_exp2f)
  return __builtin_amdgcn_exp2f(a);
#else
  return exp2f(a);
#endif
}

// monotone float <-> uint mapping for atomic min/max (valid for all floats;
// for x>=0 fenc(x)>=0x80000000 so 0-init is the max-identity)
__device__ __forceinline__ u32 fenc(float f){
  u32 u = __float_as_uint(f);
  return (u & 0x80000000u) ? ~u : (u | 0x80000000u);
}
__device__ __forceinline__ float fdec(u32 k){
  return __uint_as_float((k & 0x80000000u) ? (k ^ 0x80000000u) : ~k);
}

// ws layout:
// u32[0]        max key        (memset 0x00)
// u32[1]        done counter   (memset 0x00)
// u32[2..130)   train-result per-f atomicMax slots (fenc, memset 0x00)
// u32[130..258) test-result  per-f atomicMax slots
// u32[264]      min key        (memset 0xFF)
// f  [272..312) stdsum[40]     (written unconditionally by k_pre std blocks)
// f  [512..512+2621440) projT[E][L][F][M] (unscaled, m contiguous)

// blocks 0..1279: MFMA f16 GEMM tile (direct global loads/stores) + min/max atomics
// blocks 1280..1319: per-(e,l) std fully reduced to one float
__global__ __launch_bounds__(256) void k_pre(const float* __restrict__ mat,
                       const float* __restrict__ par,
                       float* __restrict__ projT, float* __restrict__ wsf){
  __shared__ float sm[512];
  int b = blockIdx.x, tid = threadIdx.x;
  if (b >= 1280){
    int el = b - 1280;
    int f = tid & 127, part = tid >> 7;
    const float* base = mat + ((size_t)el * M_ + part*256) * F_;
    float s = 0.f, s2 = 0.f;
    for (int i = 0; i < 256; i++){
      float v = base[i*F_ + f];
      s += v; s2 += v*v;
    }
    sm[tid] = s; sm[256 + tid] = s2;
    __syncthreads();
    if (tid < 128){
      float a1 = sm[tid] + sm[tid+128];
      float a2 = sm[256+tid] + sm[384+tid];
      float mean = a1 * (1.0f/512.0f);
      float var  = a2 * (1.0f/512.0f) - mean*mean;
      sm[tid] = sqrtf(fmaxf(var, 0.0f));
    }
    __syncthreads();
    for (int g = 64; g >= 1; g >>= 1){
      if (tid < g) sm[tid] += sm[tid+g];
      __syncthreads();
    }
    if (tid == 0) wsf[272 + el] = sm[0];
    return;
  }
  int el = b >> 5, mt = (b & 31) * 16;
  int lane = tid & 63, wave = tid >> 6;
  int q = (lane >> 4) & 3, m16 = lane & 15;
  const float* arow = mat + ((size_t)el * M_ + mt + m16) * F_;
  v4f acc0 = {0.f,0.f,0.f,0.f}, acc1 = {0.f,0.f,0.f,0.f};
  #pragma unroll
  for (int c = 0; c < 4; c++){
    float4 a0 = *(const float4*)&arow[c*32 + q*8];
    float4 a1 = *(const float4*)&arow[c*32 + q*8 + 4];
    v8h af, b0, b1;
    af[0]=(f16)a0.x; af[1]=(f16)a0.y; af[2]=(f16)a0.z; af[3]=(f16)a0.w;
    af[4]=(f16)a1.x; af[5]=(f16)a1.y; af[6]=(f16)a1.z; af[7]=(f16)a1.w;
    const float* pb = par + (c*32 + q*8)*F_ + wave*32 + m16;
    #pragma unroll
    for (int j = 0; j < 8; j++){
      b0[j] = (f16)pb[j*F_];
      b1[j] = (f16)pb[j*F_ + 16];
    }
    acc0 = __builtin_amdgcn_mfma_f32_16x16x32_f16(af, b0, acc0, 0, 0, 0);
    acc1 = __builtin_amdgcn_mfma_f32_16x16x32_f16(af, b1, acc1, 0, 0, 0);
  }
  // direct stores: C/D row=q*4+r (m), col=m16 (n) -> projT[el][n][m]
  *(float4*)(projT + ((size_t)el*F_ + wave*32      + m16)*M_ + mt + q*4)
      = make_float4(acc0[0], acc0[1], acc0[2], acc0[3]);
  *(float4*)(projT + ((size_t)el*F_ + wave*32 + 16 + m16)*M_ + mt + q*4)
      = make_float4(acc1[0], acc1[1], acc1[2], acc1[3]);
  float lmin =  3.4e38f, lmax = -3.4e38f;
  #pragma unroll
  for (int r = 0; r < 4; r++){
    lmin = fminf(lmin, fminf(acc0[r], acc1[r]));
    lmax = fmaxf(lmax, fmaxf(acc0[r], acc1[r]));
  }
  #pragma unroll
  for (int d = 32; d >= 1; d >>= 1){
    lmin = fminf(lmin, __shfl_xor(lmin, d, 64));
    lmax = fmaxf(lmax, __shfl_xor(lmax, d, 64));
  }
  if (lane == 0){ sm[wave] = lmin; sm[8+wave] = lmax; }
  __syncthreads();
  if (tid == 0){
    float mn = fminf(fminf(sm[0], sm[1]), fminf(sm[2], sm[3]));
    float mx = fmaxf(fmaxf(sm[8], sm[9]), fmaxf(sm[10], sm[11]));
    atomicMin(&((u32*)wsf)[264], fenc(mn));
    atomicMax(&((u32*)wsf)[0],   fenc(mx));
  }
}

// KDE + per-block finalize + last-block scalar reduction.
// smem: st[4][256] [0..1024) | hist 4x656 [1024..3648) | taps(128) [3648..3776) |
//       corr [3776..4032) | red [4032..4064)
__global__ __launch_bounds__(256) void k_kde(const float* __restrict__ projT,
                      const int* __restrict__ dlen, const int* __restrict__ istr,
                      float* __restrict__ wsf, float* __restrict__ out,
                      float k2c, float divisor){
  __shared__ __align__(16) float smem[4064];
  __shared__ int sflag;
  int b = blockIdx.x;          // 0..1279
  int l = b >> 7, f = b & 127;
  int tid = threadIdx.x, wave = tid >> 6, lane = tid & 63;
  u32* wsu = (u32*)wsf;
  // issue sample loads early (wave = env; column is m-contiguous)
  const float4* col = (const float4*)(projT + (((size_t)wave * L_ + l) * F_ + f) * M_);
  float4 p0 = col[lane], p1 = col[lane + 64];
  // cheap prologue: 42 wave-uniform scalar loads
  float mx = fdec(wsu[0]);
  float mn = fdec(wsu[264]);
  float ssum = 0.f;
  #pragma unroll
  for (int j = 0; j < 40; j++) ssum += wsf[272 + j];
  float rstd   = 5120.0f / ssum;
  float leftS  = mn * rstd, rightS = mx * rstd;
  float stepFS = (rightS - leftS) * (1.0f/999.0f);
  float inv2   = 1.0f / (2.0f * stepFS);
  float posScale = rstd * inv2, posOff = leftS * inv2;
  float hscale = ((rightS - leftS) * (1.0f/1000.0f)) * 0.5f / divisor;
  // zero hist + build tap/corr tables
  for (int idx = tid; idx < 656; idx += 256)
    ((float4*)(smem + 1024))[idx] = make_float4(0.f,0.f,0.f,0.f);
  float sh = 2.0f * stepFS;
  if (tid < 64){
    int u = tid - 32;
    float d0 = (float)(2*u)   * sh;
    float d1 = (float)(2*u-1) * sh;
    *(float2*)&smem[3648 + 2*tid] =
        make_float2(fexp2(k2c*d0*d0), fexp2(k2c*d1*d1));
  }
  {
    float xc = fmaf((float)(tid - 1), 4.0f*stepFS, leftS);
    smem[3776 + tid] = fexp2(k2c * xc * xc);
  }
  __syncthreads();
  // quadratic (TSC) splat straight from registers; wave owns env's histogram
  {
    float* hf = smem + 1024 + wave*656;
    float pv[8] = {p0.x,p0.y,p0.z,p0.w,p1.x,p1.y,p1.z,p1.w};
    #pragma unroll
    for (int i = 0; i < 8; i++){
      float pos = fmaf(pv[i], posScale, -posOff);
      float n = floorf(pos + 0.5f);
      float d = pos - n;
      float wm = 0.5f*(0.5f-d)*(0.5f-d);
      float wp = 0.5f*(0.5f+d)*(0.5f+d);
      float w0 = 0.75f - d*d;
      int base = (int)n + 71;
      atomicAdd(&hf[base  ], wm);
      atomicAdd(&hf[base+1], w0);
      atomicAdd(&hf[base+2], wp);
    }
  }
  __syncthreads();
  // 64-tap FIR (~±3.8σ), node c = lane + 64k
  float lenE = (float)dlen[wave*L_ + l];
  float rlen = 1.0f / lenE;
  float padc = 512.0f - lenE;
  {
    const float* sK = smem + 3648;
    const float* hb = smem + 1024 + wave*656;
    float a0=0.f, a1=0.f, a2=0.f, a3=0.f;
    #pragma unroll 8
    for (int uu = 0; uu < 64; uu++){
      float2 kv = *(const float2*)&sK[2*uu];
      int off = 2*(67 - uu) + 2*lane;
      float2 h0 = *(const float2*)&hb[off];
      float2 h1 = *(const float2*)&hb[off + 128];
      float2 h2 = *(const float2*)&hb[off + 256];
      float2 h3 = *(const float2*)&hb[off + 384];
      a0 = fmaf(h0.x, kv.x, fmaf(h0.y, kv.y, a0));
      a1 = fmaf(h1.x, kv.x, fmaf(h1.y, kv.y, a1));
      a2 = fmaf(h2.x, kv.x, fmaf(h2.y, kv.y, a2));
      a3 = fmaf(h3.x, kv.x, fmaf(h3.y, kv.y, a3));
    }
    const float* sCorr = smem + 3776;
    smem[wave*256 + lane      ] = (a0 - padc * sCorr[lane      ]) * rlen;
    smem[wave*256 + lane +  64] = (a1 - padc * sCorr[lane +  64]) * rlen;
    smem[wave*256 + lane + 128] = (a2 - padc * sCorr[lane + 128]) * rlen;
    smem[wave*256 + lane + 192] = (a3 - padc * sCorr[lane + 192]) * rlen;
  }
  __syncthreads();
  // fine grid: 4-pt Lagrange cubic on st, then pairwise L1
  float ps[6] = {0,0,0,0,0,0};
  #pragma unroll
  for (int r=0;r<4;r++){
    int t = tid + 256*r;
    if (t < S_){
      int cc = t >> 2;
      float u = (float)(t & 3) * 0.25f;
      float um1 = u - 1.0f, um2 = u - 2.0f, up1 = u + 1.0f;
      float w0 = -u * um1 * um2 * (1.0f/6.0f);
      float w1 = up1 * um1 * um2 * 0.5f;
      float w2 = -u * up1 * um2 * 0.5f;
      float w3 = u * up1 * um1 * (1.0f/6.0f);
      float rr[4];
      #pragma unroll
      for (int e=0;e<4;e++){
        const float* st = &smem[e*256 + cc];
        rr[e] = w0*st[0] + w1*st[1] + w2*st[2] + w3*st[3];
      }
      ps[0] += fabsf(rr[0]-rr[1]);
      ps[1] += fabsf(rr[0]-rr[2]);
      ps[2] += fabsf(rr[0]-rr[3]);
      ps[3] += fabsf(rr[1]-rr[2]);
      ps[4] += fabsf(rr[1]-rr[3]);
      ps[5] += fabsf(rr[2]-rr[3]);
    }
  }
  #pragma unroll
  for (int pr=0; pr<6; pr++){
    float v = ps[pr];
    #pragma unroll
    for (int d=32; d>=1; d>>=1) v += __shfl_xor(v, d, 64);
    if (lane == 0) smem[4032 + wave*8 + pr] = v;
  }
  __syncthreads();
  // per-block finalize: this block IS (l,f) — max over pairs needs no other block
  if (tid == 0){
    bool t0 = istr[0]!=0, t1 = istr[1]!=0, t2 = istr[2]!=0, t3 = istr[3]!=0;
    bool trn[6] = { t0&&t1, t0&&t2, t0&&t3, t1&&t2, t1&&t3, t2&&t3 };
    float tmax = -INFINITY, trmax = -INFINITY;
    #pragma unroll
    for (int pr=0;pr<6;pr++){
      float h = (smem[4032+pr] + smem[4040+pr] + smem[4048+pr] + smem[4056+pr]) * hscale;
      tmax = fmaxf(tmax, h);
      if (trn[pr]) trmax = fmaxf(trmax, h);
    }
    out[b]        = trmax;   // train_results[l,f]
    out[1280 + b] = tmax;    // test_results[l,f]
    atomicMax(&wsu[2   + f], fenc(trmax));   // max over l, per f (values >= 0)
    atomicMax(&wsu[130 + f], fenc(tmax));
    __threadfence();                          // release: slots before counter
    u32 old = atomicAdd(&wsu[1], 1u);
    sflag = (old == 1279u);
  }
  __syncthreads();
  if (sflag){   // last block: reduce per-f slots -> 2 scalars
    __threadfence();                          // acquire
    if (tid < 128){
      smem[tid]       = fdec(atomicOr(&wsu[2   + tid], 0u));
      smem[128 + tid] = fdec(atomicOr(&wsu[130 + tid], 0u));
    }
    __syncthreads();
    for (int g = 64; g >= 1; g >>= 1){
      if (tid < g){ smem[tid] += smem[tid+g]; smem[128+tid] += smem[128+tid+g]; }
      __syncthreads();
    }
    if (tid == 0){
      out[2560] = smem[0]   * (1.0f/128.0f);   // train_dis
      out[2561] = smem[128] * (1.0f/128.0f);   // test_dis
    }
  }
}

extern "C" void kernel_launch(void* const* d_in, const int* in_sizes, int n_in,
                              void* d_out, int out_size, void* d_ws, size_t ws_size,
                              hipStream_t stream){
  const float* mat = (const float*)d_in[0];
  const float* par = (const float*)d_in[1];
  const int*  dlen = (const int*)d_in[2];
  const int*  istr = (const int*)d_in[3];
  float* out = (float*)d_out;
  float* wsf = (float*)d_ws;
  float* projT = wsf + 512;

  // host-computable constants (bw's data-dependent factor is identically 1)
  double bw_d   = 1.06 * pow(512.0, -0.2);
  float  bw     = (float)bw_d;
  float  offset = expf(-0.5f / (bw*bw));
  float  k2c    = (float)(log((double)offset) * 1.4426950408889634);  // log2(offset)
  float  divisor = sqrtf(6.283185307179586f) * bw;

  // init: keys/counter/slots zero, min-key 0xFFFFFFFF
  hipMemsetAsync(wsf, 0, 1056, stream);
  hipMemsetAsync((char*)wsf + 1056, 0xFF, 4, stream);

  k_pre <<<1320, 256, 0, stream>>>(mat, par, projT, wsf);
  k_kde <<<1280, 256, 0, stream>>>(projT, dlen, istr, wsf, out, k2c, divisor);
}